// Round 16
// baseline (152.732 us; speedup 1.0000x reference)
//
#include <hip/hip_runtime.h>
#include <math.h>

#define EPSF 2.2e-10f
#define NV 30000
#define NVP 30080
#define NB 512

typedef __attribute__((ext_vector_type(8))) short short8;
typedef __attribute__((ext_vector_type(4))) float f32x4;
typedef __attribute__((ext_vector_type(4))) unsigned short ushort4v;

__device__ __forceinline__ unsigned short f2bf(float f) {
    unsigned int u = __float_as_uint(f);
    u += 0x7fffu + ((u >> 16) & 1u);
    return (unsigned short)(u >> 16);
}
__device__ __forceinline__ float bf2f(unsigned short h) {
    return __uint_as_float((unsigned int)h << 16);
}

// ---------------------------------------------------------------- digamma
__device__ __forceinline__ float digammaf(float xx) {
    float x = xx, r = 0.f;
    while (x < 6.f) { r -= 1.f / x; x += 1.f; }
    float f = 1.f / (x * x);
    float s = logf(x) - 0.5f / x
        - f * (0.0833333333f - f * (0.0083333333f - f * (0.0039682540f
        - f * (0.0041666667f - f * 0.0075757576f))));
    return r + s;
}

// dual-xor swizzle: conflict-free for row-staging, transpose-gather, and MFMA frag reads
#define PRE(v,k) ((((v) << 8) + ((k) << 1)) ^ (((((v) & 7) ^ (((v) >> 3) & 7))) << 4))

// ================================================================ kPre: phi0->phi_bf + phiT + Sphi/Snz partials | theta conversions
// blocks 0..234: 128 v-rows each. blocks 235..266: theta (512 thr each).
__global__ __launch_bounds__(512) void kPre(
    const float* __restrict__ phi0,      // (NV,128)
    const float* __restrict__ noise0,    // (NV,128)
    const float* __restrict__ th,        // (128,512)
    unsigned short* __restrict__ phi_bf, // (NV,128) bf16
    unsigned short* __restrict__ phiT,   // (128,NVP) bf16
    unsigned short* __restrict__ th_bf,  // (128,512) bf16
    unsigned short* __restrict__ thT_bf, // (512,128) bf16
    float* __restrict__ Sp_part,         // (235,128)
    float* __restrict__ Sn_part)         // (235,128)
{
    const int t = threadIdx.x;
    if (blockIdx.x >= 235) {
        int idx = (blockIdx.x - 235) * 512 + t;   // 16384
        int k = idx >> 7, b4 = (idx & 127) << 2;
        float4 v = *(const float4*)&th[k * NB + b4];
        ushort4v h = { f2bf(v.x), f2bf(v.y), f2bf(v.z), f2bf(v.w) };
        *(ushort4v*)&th_bf[k * NB + b4] = h;
#pragma unroll
        for (int i = 0; i < 4; ++i) thT_bf[(b4 + i) * 128 + k] = h[i];
        return;
    }
    __shared__ __align__(16) unsigned char lds[34816];   // 32KB tile + 2KB red
    const int vbase = blockIdx.x << 7;

    // stage phi tile (128 v x 128 k) as bf16, swizzled
    for (int idx = t; idx < 2048; idx += 512) {
        int v = idx >> 4, k0 = (idx & 15) << 3;
        int vg = vbase + v;
        float4 a = {0,0,0,0}, b = {0,0,0,0};
        if (vg < NV) {
            a = *(const float4*)&phi0[(size_t)vg * 128 + k0];
            b = *(const float4*)&phi0[(size_t)vg * 128 + k0 + 4];
        }
        ushort4v h0 = { f2bf(a.x), f2bf(a.y), f2bf(a.z), f2bf(a.w) };
        ushort4v h1 = { f2bf(b.x), f2bf(b.y), f2bf(b.z), f2bf(b.w) };
        *(ushort4v*)&lds[PRE(v, k0)]     = h0;
        *(ushort4v*)&lds[PRE(v, k0 + 4)] = h1;
    }
    __syncthreads();
    // phi_bf rows (sequential 32KB per block)
    for (int idx = t; idx < 2048; idx += 512) {
        int v = idx >> 4, k0 = (idx & 15) << 3;
        int vg = vbase + v;
        if (vg < NV)
            *(short8*)&phi_bf[(size_t)vg * 128 + k0] = *(const short8*)&lds[PRE(v, k0)];
    }
    // phiT rows (transpose gather; 256B runs per k)
    for (int idx = t; idx < 2048; idx += 512) {
        int k = idx >> 4, v8 = (idx & 15) << 3;
        ushort4v ha, hb;
#pragma unroll
        for (int j = 0; j < 4; ++j) {
            ha[j] = *(const unsigned short*)&lds[PRE(v8 + j, k)];
            hb[j] = *(const unsigned short*)&lds[PRE(v8 + 4 + j, k)];
        }
        *(ushort4v*)&phiT[(size_t)k * NVP + vbase + v8]     = ha;
        *(ushort4v*)&phiT[(size_t)k * NVP + vbase + v8 + 4] = hb;
    }
    // Sphi / Snz partials (no atomics)
    const int kf = t & 127, vgr = t >> 7;   // 4 groups of 32 v
    float sp = 0.f, sn = 0.f;
#pragma unroll
    for (int vi = 0; vi < 32; ++vi) {
        int v = (vgr << 5) + vi;
        int vg = vbase + v;
        if (vg < NV) {
            float ph = bf2f(*(const unsigned short*)&lds[PRE(v, kf)]);
            sp += ph;
            sn += sqrtf(ph) * noise0[(size_t)vg * 128 + kf];
        }
    }
    float* red = (float*)&lds[32768];
    red[t] = sp;
    __syncthreads();
    if (t < 128) Sp_part[blockIdx.x * 128 + t] =
        (red[t] + red[t + 128]) + (red[t + 256] + red[t + 384]);
    __syncthreads();
    red[t] = sn;
    __syncthreads();
    if (t < 128) Sn_part[blockIdx.x * 128 + t] =
        (red[t] + red[t + 128]) + (red[t + 256] + red[t + 384]);
}

// ================================================================ kA1: pure denom GEMM
// Grid 235 vtiles x 4 bslices; 512 threads (8 waves). Wave owns 16 b-rows x 128 v.
// Stages bf16 phi directly (no cvt); denomT store runs are 256B.
__global__ __launch_bounds__(512, 8) void kA1(
    const unsigned short* __restrict__ phi_bf, // (NV,128) bf16
    const unsigned short* __restrict__ thT_bf, // (512,128)
    unsigned short* __restrict__ denomT)       // (B,NVP) bf16  (= ratioT buffer)
{
    __shared__ __align__(16) unsigned char lds[32768];
    const int t = threadIdx.x, lane = t & 63, w = t >> 6;
    const int lrow = lane & 15, hi = lane >> 4;
    const int lkb = hi << 3, lcq = hi << 2;
    const int vbase = (blockIdx.x >> 2) << 7;
    const int bslice = blockIdx.x & 3;
    const int bb = (bslice << 7) + (w << 4);   // wave's 16 b-rows

    // stage phi (128 v-rows) bf16 -> LDS (zero pad beyond NV)
    for (int idx = t; idx < 2048; idx += 512) {
        int v = idx >> 4, k0 = (idx & 15) << 3;
        int vg = vbase + v;
        short8 val = {0,0,0,0,0,0,0,0};
        if (vg < NV) val = *(const short8*)&phi_bf[(size_t)vg * 128 + k0];
        *(short8*)&lds[PRE(v, k0)] = val;
    }
    __syncthreads();

    // denom MFMA: 8 v-frags x full K=128
    f32x4 dacc[8];
#pragma unroll
    for (int vg = 0; vg < 8; ++vg) dacc[vg] = (f32x4){0.f, 0.f, 0.f, 0.f};
#pragma unroll
    for (int ks = 0; ks < 4; ++ks) {
        short8 bt = *(const short8*)&thT_bf[(size_t)(bb + lrow) * 128 + (ks << 5) + lkb];
#pragma unroll
        for (int vg = 0; vg < 8; ++vg) {
            short8 pa = *(const short8*)&lds[PRE(vg * 16 + lrow, (ks << 5) + lkb)];
            dacc[vg] = __builtin_amdgcn_mfma_f32_16x16x32_bf16(pa, bt, dacc[vg], 0, 0, 0);
        }
    }
    // store raw denom bf16 (rows get 256B runs)
#pragma unroll
    for (int vg = 0; vg < 8; ++vg) {
        ushort4v h;
#pragma unroll
        for (int i = 0; i < 4; ++i) h[i] = f2bf(dacc[vg][i]);
        *(ushort4v*)&denomT[(size_t)(bb + lrow) * NVP + vbase + vg * 16 + lcq] = h;
    }
}

// ================================================================ kA2: ratio = x * rcp(max(denom,eps)) in place | +Sphi/Snz reducer
__global__ __launch_bounds__(256, 8) void kA2(
    const float* __restrict__ x,          // (B,NV)
    unsigned short* __restrict__ ratioT,  // (B,NVP) bf16: denom in, ratio out
    const float* __restrict__ Sp_part, const float* __restrict__ Sn_part,
    float* __restrict__ Sphi, float* __restrict__ Snz)
{
    if (blockIdx.x == 2048) {
        const int t = threadIdx.x;
        if (t < 128) {
            float s = 0.f;
            for (int i = 0; i < 235; ++i) s += Sp_part[i * 128 + t];
            Sphi[t] = s;
        } else {
            const int k = t - 128;
            float s = 0.f;
            for (int i = 0; i < 235; ++i) s += Sn_part[i * 128 + k];
            Snz[k] = s;
        }
        return;
    }
    const int b = blockIdx.x >> 2;
    const int q = blockIdx.x & 3;
    const float* xr = x + (size_t)b * NV;
    unsigned short* rr = ratioT + (size_t)b * NVP;
    const int base = q * 7500;            // 1875 f32x4 per quarter
#pragma unroll
    for (int i = 0; i < 8; ++i) {
        int vi = i * 256 + threadIdx.x;
        if (vi < 1875) {
            int v = base + vi * 4;
            f32x4 xv = *(const f32x4*)&xr[v];
            ushort4v dh = *(const ushort4v*)&rr[v];
            ushort4v h;
#pragma unroll
            for (int j = 0; j < 4; ++j) {
                float den = fmaxf(bf2f(dh[j]), EPSF);
                h[j] = f2bf(xv[j] * __builtin_amdgcn_rcpf(den));
            }
            *(ushort4v*)&rr[v] = h;
        }
    }
}

// ================================================================ kBC: kB (blocks 0..469) + k2 (blocks 470..1109)
#define KB_RT(v,b) ((((v) << 7) + ((b) << 1)) ^ (((((v) & 7) ^ (((v) >> 3) & 7))) << 4))
#define KB_R0(v,k) ((((v) << 9) + ((k) << 2)) ^ (((v) & 7) << 4))
#define K2_PH(k,v) ((((k) << 7) + ((v) << 1)) ^ (((k) & 7) << 4))
#define K2_RT(b,v) ((16384 + ((b) << 7) + ((v) << 1)) ^ (((b) & 7) << 4))

__global__ __launch_bounds__(512, 4) void kBC(
    const unsigned short* __restrict__ ratioT, // (B,NVP) bf16
    const unsigned short* __restrict__ th_bf,  // (128,512) bf16
    const unsigned short* __restrict__ phiT,   // (128,NVP) bf16
    const float* __restrict__ phi0,            // (NV,128)
    float* __restrict__ R0,                    // (NV,128) = d_out region
    float* __restrict__ NDot0,                 // (128)
    float* __restrict__ part)                  // (80,128,512)
{
    __shared__ __align__(16) unsigned char lds[32768];
    const int t = threadIdx.x, lane = t & 63, w = t >> 6;
    const int lrow = lane & 15, hi = lane >> 4;
    const int lkb = hi << 3, lcq = hi << 2;

    if (blockIdx.x < 470) {
        // ---------------- kB path ----------------
        const int vbase = blockIdx.x << 6;
        f32x4 racc[4];
#pragma unroll
        for (int vf = 0; vf < 4; ++vf) racc[vf] = (f32x4){0.f, 0.f, 0.f, 0.f};

        for (int c = 0; c < 8; ++c) {
            const int bs = c << 6;
            __syncthreads();
            {
                int b = t >> 3, v8 = (t & 7) << 3;
                short8 val = *(const short8*)&ratioT[(size_t)(bs + b) * NVP + vbase + v8];
#pragma unroll
                for (int j = 0; j < 8; ++j)
                    *(unsigned short*)&lds[KB_RT(v8 + j, b)] = ((unsigned short*)&val)[j];
            }
            __syncthreads();
#pragma unroll
            for (int ks = 0; ks < 2; ++ks) {
                short8 a0 = *(const short8*)&th_bf[(size_t)(w * 16 + lrow) * NB + bs + (ks << 5) + lkb];
#pragma unroll
                for (int vf = 0; vf < 4; ++vf) {
                    short8 bb = *(const short8*)&lds[KB_RT(vf * 16 + lrow, (ks << 5) + lkb)];
                    racc[vf] = __builtin_amdgcn_mfma_f32_16x16x32_bf16(a0, bb, racc[vf], 0, 0, 0);
                }
            }
        }
        __syncthreads();
#pragma unroll
        for (int vf = 0; vf < 4; ++vf)
            *(f32x4*)&lds[KB_R0(vf * 16 + lrow, w * 16 + lcq)] = racc[vf];
        __syncthreads();
        const int kf = t & 127;
        float nd = 0.f;
        for (int idx = t; idx < 8192; idx += 512) {
            int v = idx >> 7;
            int vg = vbase + v;
            if (vg < NV) {
                float r0v = *(const float*)&lds[KB_R0(v, kf)];
                R0[(size_t)vg * 128 + kf] = r0v;
                nd += r0v * phi0[(size_t)vg * 128 + kf];
            }
        }
        __syncthreads();
        float* red = (float*)lds;
        red[t] = nd;
        __syncthreads();
        if (t < 128) atomicAdd(&NDot0[t], 100.f * ((red[t] + red[t + 128]) + (red[t + 256] + red[t + 384])));
    } else {
        // ---------------- k2 path ----------------
        const int bid2 = blockIdx.x - 470;
        const int btile = bid2 & 7;     // 8 b-tiles of 64
        const int split = bid2 >> 3;    // 80 splits
        const int b0 = btile << 6;

        f32x4 acc[4];
#pragma unroll
        for (int bt = 0; bt < 4; ++bt) acc[bt] = (f32x4){0.f, 0.f, 0.f, 0.f};

        for (int ci = split; ci < 470; ci += 80) {
            const int v0 = ci << 6;
            __syncthreads();
            for (int idx = t; idx < 1024; idx += 512) {
                int k = idx >> 3, v8 = (idx & 7) << 3;
                *(short8*)&lds[K2_PH(k, v8)] =
                    *(const short8*)&phiT[(size_t)k * NVP + v0 + v8];
            }
            {
                int b = t >> 3, v8 = (t & 7) << 3;
                *(short8*)&lds[K2_RT(b, v8)] =
                    *(const short8*)&ratioT[(size_t)(b0 + b) * NVP + v0 + v8];
            }
            __syncthreads();
#pragma unroll
            for (int vs = 0; vs < 2; ++vs) {
                short8 a0 = *(const short8*)&lds[K2_PH(w * 16 + lrow, (vs << 5) + lkb)];
#pragma unroll
                for (int bt = 0; bt < 4; ++bt) {
                    short8 bb = *(const short8*)&lds[K2_RT(bt * 16 + lrow, (vs << 5) + lkb)];
                    acc[bt] = __builtin_amdgcn_mfma_f32_16x16x32_bf16(a0, bb, acc[bt], 0, 0, 0);
                }
            }
        }
        float* dst = part + (size_t)split * 65536;
#pragma unroll
        for (int bt = 0; bt < 4; ++bt)
#pragma unroll
            for (int i = 0; i < 4; ++i)
                dst[(w * 16 + lcq + i) * NB + b0 + bt * 16 + lrow] = acc[bt][i];
    }
}

// ================================================================ k3456: k345 (blocks 0..1874) + k6 (blocks 1875..2130)
__global__ __launch_bounds__(256) void k3456(
    const float* __restrict__ phi0, const float* __restrict__ noise0,
    const float* __restrict__ NDot0, const float* __restrict__ Sphi,
    const float* __restrict__ Snz, float* __restrict__ out,
    const float* __restrict__ phi1, const float* __restrict__ theta1,
    const float* __restrict__ theta0, const float* __restrict__ part,
    float* __restrict__ ratio1)
{
    const int t = threadIdx.x;
    if (blockIdx.x < 1875) {
        const int k = t & 127;
        const size_t base = (size_t)blockIdx.x * 2048;
        float ndv = NDot0[k];
        float inv_n = 1.f / fmaxf(ndv, EPSF);
        float tmpsum = ndv + 3000.f;
        float sp = Sphi[k], sn = Snz[k];
        float stepsum = sp + inv_n * tmpsum * (1.f - sp) + sqrtf(2.f * inv_n) * sn;
        float ssm1 = stepsum - 1.f;
        float psum = stepsum - ssm1 * sp;
        float inv = 1.f / fmaxf(psum, EPSF);
#pragma unroll
        for (int i = 0; i < 8; ++i) {
            size_t e = base + i * 256 + t;
            float phi = phi0[e], R = out[e], nz = noise0[e];
            float tmp = fmaf(100.f * phi, R, 0.1f);
            float step = phi + inv_n * (tmp - tmpsum * phi) + sqrtf(2.f * inv_n * phi) * nz;
            float p = fmaxf(EPSF, step - ssm1 * phi);
            out[e] = p * inv;
        }
    } else {
        int g = (blockIdx.x - 1875) * 256 + t;       // 128*512
        int d = g >> 9, b = g & 511;
        float c0a = 0.f, c0b = 0.f, c0c = 0.f, c0d = 0.f;
        for (int s = 0; s < 80; s += 4) {
            c0a += part[(size_t)s * 65536 + g];
            c0b += part[(size_t)(s + 1) * 65536 + g];
            c0c += part[(size_t)(s + 2) * 65536 + g];
            c0d += part[(size_t)(s + 3) * 65536 + g];
        }
        float c0 = (c0a + c0b) + (c0c + c0d);
        float denom = 0.f;
        for (int k = 0; k < 64; ++k) denom = fmaf(phi1[d * 64 + k], theta1[k * NB + b], denom);
        denom = fmaxf(denom, EPSF);
        float xc = theta0[g] * c0;
        ratio1[g] = digammaf(denom + xc) - digammaf(denom);
    }
}

// ---------------------------------------------------------------- k78: R1 + NDot1 partials (blocks 0..255) | x2v (blocks 256..383)
__global__ __launch_bounds__(256) void k78(
    const float* __restrict__ ratio1, const float* __restrict__ theta1,
    const float* __restrict__ phi1, float* __restrict__ R1,
    float* __restrict__ ndp1, float* __restrict__ x2v)
{
    if (blockIdx.x < 256) {
        const int wid = (blockIdx.x << 2) + (threadIdx.x >> 6);  // 0..1023
        const int lane = threadIdx.x & 63;
        const int kk = wid & 63, dg = wid >> 6;                  // dg 0..15
        float th[8];
#pragma unroll
        for (int j = 0; j < 8; ++j) th[j] = theta1[kk * NB + j * 64 + lane];
        float ndp = 0.f;
#pragma unroll
        for (int dd = 0; dd < 8; ++dd) {
            int d = dg * 8 + dd;
            float s = 0.f;
#pragma unroll
            for (int j = 0; j < 8; ++j)
                s = fmaf(ratio1[d * NB + j * 64 + lane], th[j], s);
#pragma unroll
            for (int o = 1; o < 64; o <<= 1) s += __shfl_xor(s, o);
            if (lane == dd) {
                R1[d * 64 + kk] = s;
                ndp = phi1[d * 64 + kk] * s;
            }
        }
#pragma unroll
        for (int o = 1; o < 8; o <<= 1) ndp += __shfl_xor(ndp, o);
        if (lane == 0) ndp1[dg * 64 + kk] = 100.f * ndp;
    } else {
        int g = (blockIdx.x - 256) * 256 + threadIdx.x;  // 64*512
        int kk = g >> 9, b = g & 511;
        float s0 = 0.f, s1 = 0.f, s2 = 0.f, s3 = 0.f;
#pragma unroll 4
        for (int d = 0; d < 128; d += 4) {
            s0 = fmaf(phi1[d * 64 + kk],       ratio1[d * NB + b],       s0);
            s1 = fmaf(phi1[(d + 1) * 64 + kk], ratio1[(d + 1) * NB + b], s1);
            s2 = fmaf(phi1[(d + 2) * 64 + kk], ratio1[(d + 2) * NB + b], s2);
            s3 = fmaf(phi1[(d + 3) * 64 + kk], ratio1[(d + 3) * NB + b], s3);
        }
        x2v[g] = theta1[g] * ((s0 + s1) + (s2 + s3));
    }
}

// k10 (blocks 0..127) + tlasgr layer1 (blocks 128..159)
__global__ __launch_bounds__(256) void k10t1(
    const float* __restrict__ phi2, const float* __restrict__ theta2,
    const float* __restrict__ x2v, float* __restrict__ ratio2,
    const float* __restrict__ phi1, const float* __restrict__ R1,
    const float* __restrict__ noise1, const float* __restrict__ ndp1,
    float* __restrict__ out1)
{
    __shared__ float red[8];
    if (blockIdx.x < 128) {
        int g = blockIdx.x * 256 + threadIdx.x;       // 64*512
        int d = g >> 9, b = g & 511;
        float denom = 0.f;
        for (int k = 0; k < 32; ++k) denom = fmaf(phi2[d * 32 + k], theta2[k * NB + b], denom);
        denom = fmaxf(denom, EPSF);
        float xc = x2v[g];
        ratio2[g] = digammaf(denom + xc) - digammaf(denom);
    } else {
        const int t = threadIdx.x;
        const int c = t >> 7;                          // 0/1
        const int k = (blockIdx.x - 128) * 2 + c;
        const int d = t & 127;
        const int e = d * 64 + k;
        float ndv = 0.f;
#pragma unroll
        for (int i = 0; i < 16; ++i) ndv += ndp1[i * 64 + k];
        float inv_n = 1.f / fmaxf(ndv, EPSF);
        float tmpsum = ndv + 12.8f;
        float phiv = phi1[e];
        float tmp = fmaf(100.f * phiv, R1[e], 0.1f);
        float step = phiv + inv_n * (tmp - tmpsum * phiv) + sqrtf(2.f * inv_n * phiv) * noise1[e];
        float s = step;
#pragma unroll
        for (int o = 1; o < 64; o <<= 1) s += __shfl_xor(s, o);
        int slot = t >> 6;
        if ((t & 63) == 0) red[slot] = s;
        __syncthreads();
        float ssum = red[c * 2] + red[c * 2 + 1];
        float p = fmaxf(EPSF, step - (ssum - 1.f) * phiv);
        float q = p;
#pragma unroll
        for (int o = 1; o < 64; o <<= 1) q += __shfl_xor(q, o);
        if ((t & 63) == 0) red[4 + slot] = q;
        __syncthreads();
        float psum = red[4 + c * 2] + red[4 + c * 2 + 1];
        out1[e] = p / fmaxf(psum, EPSF);
    }
}

// ---------------------------------------------------------------- k11: R2 + NDot2 partials (no atomics)
__global__ __launch_bounds__(256) void k11_r2_w(
    const float* __restrict__ ratio2, const float* __restrict__ theta2,
    const float* __restrict__ phi2, float* __restrict__ R2, float* __restrict__ ndp2)
{
    const int wid = (blockIdx.x << 2) + (threadIdx.x >> 6);  // 0..255
    const int lane = threadIdx.x & 63;
    const int kk = wid & 31, dg = wid >> 5;                  // dg 0..7
    float th[8];
#pragma unroll
    for (int j = 0; j < 8; ++j) th[j] = theta2[kk * NB + j * 64 + lane];
    float ndp = 0.f;
#pragma unroll
    for (int dd = 0; dd < 8; ++dd) {
        int d = dg * 8 + dd;
        float s = 0.f;
#pragma unroll
        for (int j = 0; j < 8; ++j)
            s = fmaf(ratio2[d * NB + j * 64 + lane], th[j], s);
#pragma unroll
        for (int o = 1; o < 64; o <<= 1) s += __shfl_xor(s, o);
        if (lane == dd) {
            R2[d * 32 + kk] = s;
            ndp = phi2[d * 32 + kk] * s;
        }
    }
#pragma unroll
    for (int o = 1; o < 8; o <<= 1) ndp += __shfl_xor(ndp, o);
    if (lane == 0) ndp2[dg * 32 + kk] = 100.f * ndp;
}

// layer2 tlasgr: 4 columns per block (one wave each), D=64
__global__ __launch_bounds__(256) void t2_quad(
    const float* __restrict__ phi2, const float* __restrict__ R2,
    const float* __restrict__ noise2, const float* __restrict__ ndp2,
    float* __restrict__ out2)
{
    const int c = blockIdx.x * 4 + (threadIdx.x >> 6);
    const int d = threadIdx.x & 63;
    const int e = d * 32 + c;
    float ndv = 0.f;
#pragma unroll
    for (int i = 0; i < 8; ++i) ndv += ndp2[i * 32 + c];
    float inv_n = 1.f / fmaxf(ndv, EPSF);
    float tmpsum = ndv + 6.4f;
    float phiv = phi2[e];
    float tmp = fmaf(100.f * phiv, R2[e], 0.1f);
    float step = phiv + inv_n * (tmp - tmpsum * phiv) + sqrtf(2.f * inv_n * phiv) * noise2[e];
    float s = step;
#pragma unroll
    for (int o = 1; o < 64; o <<= 1) s += __shfl_xor(s, o);
    float p = fmaxf(EPSF, step - (s - 1.f) * phiv);
    float q = p;
#pragma unroll
    for (int o = 1; o < 64; o <<= 1) q += __shfl_xor(q, o);
    out2[e] = p / fmaxf(q, EPSF);
}

// ----------------------------------------------------------------
extern "C" void kernel_launch(void* const* d_in, const int* in_sizes, int n_in,
                              void* d_out, int out_size, void* d_ws, size_t ws_size,
                              hipStream_t stream)
{
    const float* x      = (const float*)d_in[0];
    const float* theta0 = (const float*)d_in[1];
    const float* theta1 = (const float*)d_in[2];
    const float* theta2 = (const float*)d_in[3];
    const float* phi0   = (const float*)d_in[4];
    const float* phi1   = (const float*)d_in[5];
    const float* phi2   = (const float*)d_in[6];
    const float* noise0 = (const float*)d_in[7];
    const float* noise1 = (const float*)d_in[8];
    const float* noise2 = (const float*)d_in[9];
    float* out = (float*)d_out;
    float* ws  = (float*)d_ws;

    unsigned short* ratioT = (unsigned short*)ws;              // (512,30080) bf16 = 7,700,480 fl
    unsigned short* phiT   = (unsigned short*)(ws + 7700480);  // (128,30080) bf16 = 1,925,120 fl
    unsigned short* thT_bf = (unsigned short*)(ws + 9625600);  // (512,128) = 32,768 fl
    unsigned short* th_bf  = (unsigned short*)(ws + 9658368);  // (128,512) = 32,768 fl
    float* part     = ws + 9691136;       // 80*65536 = 5,242,880
    // phi_bf OVERLAYS part[0..1,920,000): written by kPre, read by kA1,
    // clobbered by kBC (which runs strictly after kA1 on the stream).
    unsigned short* phi_bf = (unsigned short*)part;
    float* NDot0    = ws + 14934016;      // 128 (zeroed)
    float* Sphi     = ws + 14934144;      // 128 (written by kA2 reducer)
    float* Snz      = ws + 14934272;      // 128 (written by kA2 reducer)
    float* ndp1     = ws + 14934400;      // 1024
    float* ndp2     = ws + 14935424;      // 256
    float* Sp_part  = ws + 14935680;      // 30,080
    float* Sn_part  = ws + 14965760;      // 30,080
    float* ratio1   = ws + 14995840;      // 65,536
    float* R1       = ws + 15061376;      // 8,192
    float* x2v      = ws + 15069568;      // 32,768
    float* ratio2   = ws + 15102336;      // 32,768
    float* R2       = ws + 15135104;      // 2,048  -> end 15,137,152 floats (60.5 MB)

    (void)hipMemsetAsync(NDot0, 0, 128 * sizeof(float), stream);

    // prepass: phi/theta conversions + Sphi/Snz partials
    kPre<<<267, 512, 0, stream>>>(phi0, noise0, theta0, phi_bf, phiT,
                                  th_bf, thT_bf, Sp_part, Sn_part);

    // layer 0 (R0 in d_out[0..3,840,000), transformed in place by k3456)
    kA1<<<940, 512, 0, stream>>>(phi_bf, thT_bf, ratioT);
    kA2<<<2049, 256, 0, stream>>>(x, ratioT, Sp_part, Sn_part, Sphi, Snz);
    kBC<<<1110, 512, 0, stream>>>(ratioT, th_bf, phiT, phi0, out, NDot0, part);
    k3456<<<2131, 256, 0, stream>>>(phi0, noise0, NDot0, Sphi, Snz, out,
                                    phi1, theta1, theta0, part, ratio1);

    // layer 1 tail
    k78<<<384, 256, 0, stream>>>(ratio1, theta1, phi1, R1, ndp1, x2v);
    k10t1<<<160, 256, 0, stream>>>(phi2, theta2, x2v, ratio2,
                                   phi1, R1, noise1, ndp1, out + 3840000);

    // layer 2
    k11_r2_w<<<64, 256, 0, stream>>>(ratio2, theta2, phi2, R2, ndp2);
    t2_quad<<<8, 256, 0, stream>>>(phi2, R2, noise2, ndp2, out + 3848192);
}

// Round 17
// 133.680 us; speedup vs baseline: 1.1425x; 1.1425x over previous
//
#include <hip/hip_runtime.h>
#include <math.h>

#define EPSF 2.2e-10f
#define NV 30000
#define NVP 30080
#define NB 512

typedef __attribute__((ext_vector_type(8))) short short8;
typedef __attribute__((ext_vector_type(4))) float f32x4;
typedef __attribute__((ext_vector_type(4))) unsigned short ushort4v;

__device__ __forceinline__ unsigned short f2bf(float f) {
    unsigned int u = __float_as_uint(f);
    u += 0x7fffu + ((u >> 16) & 1u);
    return (unsigned short)(u >> 16);
}
__device__ __forceinline__ float bf2f(unsigned short h) {
    return __uint_as_float((unsigned int)h << 16);
}

// ---------------------------------------------------------------- digamma
__device__ __forceinline__ float digammaf(float xx) {
    float x = xx, r = 0.f;
    while (x < 6.f) { r -= 1.f / x; x += 1.f; }
    float f = 1.f / (x * x);
    float s = logf(x) - 0.5f / x
        - f * (0.0833333333f - f * (0.0083333333f - f * (0.0039682540f
        - f * (0.0041666667f - f * 0.0075757576f))));
    return r + s;
}

// ================================================================ pk_theta
__global__ __launch_bounds__(256) void pk_theta(
    const float* __restrict__ th, unsigned short* __restrict__ th_bf,
    unsigned short* __restrict__ thT_bf)
{
    int idx = blockIdx.x * 256 + threadIdx.x;   // 16384 threads
    int k = idx >> 7, b4 = (idx & 127) << 2;
    float4 v = *(const float4*)&th[k * NB + b4];
    ushort4v h = { f2bf(v.x), f2bf(v.y), f2bf(v.z), f2bf(v.w) };
    *(ushort4v*)&th_bf[k * NB + b4] = h;
#pragma unroll
    for (int i = 0; i < 4; ++i) thT_bf[(b4 + i) * 128 + k] = h[i];
}

// ================================================================ kA1: denom GEMM (+phiT, Sphi, Snz)
// XCD-chunked block remap: all 4 bslices of a vtile land on the SAME XCD
// (grid 1880 = 8 x 235), so the phi0 tile is fetched once per XCD L2.
#define K1_PHI(v,k)    ((((v) << 8) + ((k) << 1)) ^ (((v) & 7) << 4))   // 64 rows x 256B = 16KB

__global__ __launch_bounds__(512, 8) void kA1(
    const float* __restrict__ phi0,            // (NV,128)
    const unsigned short* __restrict__ thT_bf, // (512,128)
    const float* __restrict__ noise0,          // (NV,128)
    unsigned short* __restrict__ denomT,       // (B,NVP) bf16  (= ratioT buffer)
    unsigned short* __restrict__ phiT,         // (128,NVP) bf16
    float* __restrict__ Sphi,                  // (128)
    float* __restrict__ Snz)                   // (128)
{
    __shared__ __align__(16) unsigned char lds[18432];   // 16KB phi + 2KB red
    const int t = threadIdx.x, lane = t & 63, w = t >> 6;
    const int lrow = lane & 15, hi = lane >> 4;
    const int lkb = hi << 3, lcq = hi << 2;
    // XCD-chunked remap (bijective: 1880 = 8*235)
    const int slot = ((blockIdx.x & 7) * 235) + (blockIdx.x >> 3);
    const int vbase = (slot >> 2) << 6;
    const int bslice = slot & 3;
    const int bb = (bslice << 7) + (w << 4);   // wave's 16 b-rows

    // stage phi (64 v-rows) -> bf16 LDS (zero pad beyond NV)
    for (int idx = t; idx < 1024; idx += 512) {
        int v = idx >> 4, kc = (idx & 15) << 3;
        int vg = vbase + v;
        float4 a = {0,0,0,0}, b = {0,0,0,0};
        if (vg < NV) {
            a = *(const float4*)&phi0[(size_t)vg * 128 + kc];
            b = *(const float4*)&phi0[(size_t)vg * 128 + kc + 4];
        }
        ushort4v h0 = { f2bf(a.x), f2bf(a.y), f2bf(a.z), f2bf(a.w) };
        ushort4v h1 = { f2bf(b.x), f2bf(b.y), f2bf(b.z), f2bf(b.w) };
        *(ushort4v*)&lds[K1_PHI(v, kc)]     = h0;
        *(ushort4v*)&lds[K1_PHI(v, kc + 4)] = h1;
    }
    __syncthreads();

    // phiT writeout: only bslice 0
    if (bslice == 0) {
        for (int idx = t; idx < 8192; idx += 512) {
            int v = idx & 63, k = idx >> 6;
            phiT[(size_t)k * NVP + vbase + v] = *(const unsigned short*)&lds[K1_PHI(v, k)];
        }
    }

    // denom MFMA: 4 v-frags x full K=128
    f32x4 dacc[4];
#pragma unroll
    for (int vg = 0; vg < 4; ++vg) dacc[vg] = (f32x4){0.f, 0.f, 0.f, 0.f};
#pragma unroll
    for (int ks = 0; ks < 4; ++ks) {
        short8 bt = *(const short8*)&thT_bf[(size_t)(bb + lrow) * 128 + (ks << 5) + lkb];
#pragma unroll
        for (int vg = 0; vg < 4; ++vg) {
            short8 pa = *(const short8*)&lds[K1_PHI(vg * 16 + lrow, (ks << 5) + lkb)];
            dacc[vg] = __builtin_amdgcn_mfma_f32_16x16x32_bf16(pa, bt, dacc[vg], 0, 0, 0);
        }
    }
    // store raw denom bf16
#pragma unroll
    for (int vg = 0; vg < 4; ++vg) {
        ushort4v h;
#pragma unroll
        for (int i = 0; i < 4; ++i) h[i] = f2bf(dacc[vg][i]);
        *(ushort4v*)&denomT[(size_t)(bb + lrow) * NVP + vbase + vg * 16 + lcq] = h;
    }

    // Sphi + Snz epilogue: only bslice 0 (phi LDS intact)
    if (bslice == 0) {
        const int kf = t & 127, vh = t >> 7;   // 4 v-groups of 16
        float sp = 0.f, sn = 0.f;
#pragma unroll
        for (int vi = 0; vi < 16; ++vi) {
            int v = (vh << 4) + vi;
            int vg = vbase + v;
            if (vg < NV) {
                float ph = bf2f(*(const unsigned short*)&lds[K1_PHI(v, kf)]);
                sp += ph;
                sn += sqrtf(ph) * noise0[(size_t)vg * 128 + kf];
            }
        }
        float* red = (float*)&lds[16384];
        red[t] = sp;
        __syncthreads();
        if (t < 128) atomicAdd(&Sphi[t], (red[t] + red[t + 128]) + (red[t + 256] + red[t + 384]));
        __syncthreads();
        red[t] = sn;
        __syncthreads();
        if (t < 128) atomicAdd(&Snz[t], (red[t] + red[t + 128]) + (red[t + 256] + red[t + 384]));
    }
}

// ================================================================ kA2: ratio = x * rcp(max(denom,eps)), IN PLACE
__global__ __launch_bounds__(256, 8) void kA2(
    const float* __restrict__ x,          // (B,NV)
    unsigned short* __restrict__ ratioT)  // (B,NVP) bf16: denom in, ratio out
{
    const int b = blockIdx.x >> 2;
    const int q = blockIdx.x & 3;
    const float* xr = x + (size_t)b * NV;
    unsigned short* rr = ratioT + (size_t)b * NVP;
    const int base = q * 7500;            // 1875 f32x4 per quarter
#pragma unroll
    for (int i = 0; i < 8; ++i) {
        int vi = i * 256 + threadIdx.x;
        if (vi < 1875) {
            int v = base + vi * 4;
            f32x4 xv = *(const f32x4*)&xr[v];
            ushort4v dh = *(const ushort4v*)&rr[v];
            ushort4v h;
#pragma unroll
            for (int j = 0; j < 4; ++j) {
                float den = fmaxf(bf2f(dh[j]), EPSF);
                h[j] = f2bf(xv[j] * __builtin_amdgcn_rcpf(den));
            }
            *(ushort4v*)&rr[v] = h;
        }
    }
}

// ================================================================ kBC: kB (blocks 0..469) + k2 (blocks 470..1109)
// k2 portion XCD-chunked (640 = 8 x 80): all 8 btiles of a split share an XCD,
// so the split's phiT tile sequence is fetched once per XCD L2.
#define KB_RT(v,b) ((((v) << 7) + ((b) << 1)) ^ (((((v) & 7) ^ (((v) >> 3) & 7))) << 4))
#define KB_R0(v,k) ((((v) << 9) + ((k) << 2)) ^ (((v) & 7) << 4))
#define K2_PH(k,v) ((((k) << 7) + ((v) << 1)) ^ (((k) & 7) << 4))
#define K2_RT(b,v) ((16384 + ((b) << 7) + ((v) << 1)) ^ (((b) & 7) << 4))

__global__ __launch_bounds__(512, 4) void kBC(
    const unsigned short* __restrict__ ratioT, // (B,NVP) bf16
    const unsigned short* __restrict__ th_bf,  // (128,512) bf16
    const unsigned short* __restrict__ phiT,   // (128,NVP) bf16
    const float* __restrict__ phi0,            // (NV,128)
    float* __restrict__ R0,                    // (NV,128) = d_out region
    float* __restrict__ NDot0,                 // (128)
    float* __restrict__ part)                  // (80,128,512)
{
    __shared__ __align__(16) unsigned char lds[32768];
    const int t = threadIdx.x, lane = t & 63, w = t >> 6;
    const int lrow = lane & 15, hi = lane >> 4;
    const int lkb = hi << 3, lcq = hi << 2;

    if (blockIdx.x < 470) {
        // ---------------- kB path ----------------
        const int vbase = blockIdx.x << 6;
        f32x4 racc[4];
#pragma unroll
        for (int vf = 0; vf < 4; ++vf) racc[vf] = (f32x4){0.f, 0.f, 0.f, 0.f};

        for (int c = 0; c < 8; ++c) {
            const int bs = c << 6;
            __syncthreads();
            {
                int b = t >> 3, v8 = (t & 7) << 3;
                short8 val = *(const short8*)&ratioT[(size_t)(bs + b) * NVP + vbase + v8];
#pragma unroll
                for (int j = 0; j < 8; ++j)
                    *(unsigned short*)&lds[KB_RT(v8 + j, b)] = ((unsigned short*)&val)[j];
            }
            __syncthreads();
#pragma unroll
            for (int ks = 0; ks < 2; ++ks) {
                short8 a0 = *(const short8*)&th_bf[(size_t)(w * 16 + lrow) * NB + bs + (ks << 5) + lkb];
#pragma unroll
                for (int vf = 0; vf < 4; ++vf) {
                    short8 bb = *(const short8*)&lds[KB_RT(vf * 16 + lrow, (ks << 5) + lkb)];
                    racc[vf] = __builtin_amdgcn_mfma_f32_16x16x32_bf16(a0, bb, racc[vf], 0, 0, 0);
                }
            }
        }
        __syncthreads();
#pragma unroll
        for (int vf = 0; vf < 4; ++vf)
            *(f32x4*)&lds[KB_R0(vf * 16 + lrow, w * 16 + lcq)] = racc[vf];
        __syncthreads();
        const int kf = t & 127;
        float nd = 0.f;
        for (int idx = t; idx < 8192; idx += 512) {
            int v = idx >> 7;
            int vg = vbase + v;
            if (vg < NV) {
                float r0v = *(const float*)&lds[KB_R0(v, kf)];
                R0[(size_t)vg * 128 + kf] = r0v;
                nd += r0v * phi0[(size_t)vg * 128 + kf];
            }
        }
        __syncthreads();
        float* red = (float*)lds;
        red[t] = nd;
        __syncthreads();
        if (t < 128) atomicAdd(&NDot0[t], 100.f * ((red[t] + red[t + 128]) + (red[t + 256] + red[t + 384])));
    } else {
        // ---------------- k2 path ----------------
        const int bid2 = blockIdx.x - 470;
        // XCD-chunked remap (bijective: 640 = 8*80)
        const int slot = ((bid2 & 7) * 80) + (bid2 >> 3);
        const int btile = slot & 7;     // 8 b-tiles of 64
        const int split = slot >> 3;    // 80 splits
        const int b0 = btile << 6;

        f32x4 acc[4];
#pragma unroll
        for (int bt = 0; bt < 4; ++bt) acc[bt] = (f32x4){0.f, 0.f, 0.f, 0.f};

        for (int ci = split; ci < 470; ci += 80) {
            const int v0 = ci << 6;
            __syncthreads();
            for (int idx = t; idx < 1024; idx += 512) {
                int k = idx >> 3, v8 = (idx & 7) << 3;
                *(short8*)&lds[K2_PH(k, v8)] =
                    *(const short8*)&phiT[(size_t)k * NVP + v0 + v8];
            }
            {
                int b = t >> 3, v8 = (t & 7) << 3;
                *(short8*)&lds[K2_RT(b, v8)] =
                    *(const short8*)&ratioT[(size_t)(b0 + b) * NVP + v0 + v8];
            }
            __syncthreads();
#pragma unroll
            for (int vs = 0; vs < 2; ++vs) {
                short8 a0 = *(const short8*)&lds[K2_PH(w * 16 + lrow, (vs << 5) + lkb)];
#pragma unroll
                for (int bt = 0; bt < 4; ++bt) {
                    short8 bb = *(const short8*)&lds[K2_RT(bt * 16 + lrow, (vs << 5) + lkb)];
                    acc[bt] = __builtin_amdgcn_mfma_f32_16x16x32_bf16(a0, bb, acc[bt], 0, 0, 0);
                }
            }
        }
        float* dst = part + (size_t)split * 65536;
#pragma unroll
        for (int bt = 0; bt < 4; ++bt)
#pragma unroll
            for (int i = 0; i < 4; ++i)
                dst[(w * 16 + lcq + i) * NB + b0 + bt * 16 + lrow] = acc[bt][i];
    }
}

// ================================================================ k3456: k345 (blocks 0..1874) + k6 (blocks 1875..2130)
__global__ __launch_bounds__(256) void k3456(
    const float* __restrict__ phi0, const float* __restrict__ noise0,
    const float* __restrict__ NDot0, const float* __restrict__ Sphi,
    const float* __restrict__ Snz, float* __restrict__ out,
    const float* __restrict__ phi1, const float* __restrict__ theta1,
    const float* __restrict__ theta0, const float* __restrict__ part,
    float* __restrict__ ratio1)
{
    const int t = threadIdx.x;
    if (blockIdx.x < 1875) {
        const int k = t & 127;
        const size_t base = (size_t)blockIdx.x * 2048;
        float ndv = NDot0[k];
        float inv_n = 1.f / fmaxf(ndv, EPSF);
        float tmpsum = ndv + 3000.f;
        float sp = Sphi[k], sn = Snz[k];
        float stepsum = sp + inv_n * tmpsum * (1.f - sp) + sqrtf(2.f * inv_n) * sn;
        float ssm1 = stepsum - 1.f;
        float psum = stepsum - ssm1 * sp;
        float inv = 1.f / fmaxf(psum, EPSF);
#pragma unroll
        for (int i = 0; i < 8; ++i) {
            size_t e = base + i * 256 + t;
            float phi = phi0[e], R = out[e], nz = noise0[e];
            float tmp = fmaf(100.f * phi, R, 0.1f);
            float step = phi + inv_n * (tmp - tmpsum * phi) + sqrtf(2.f * inv_n * phi) * nz;
            float p = fmaxf(EPSF, step - ssm1 * phi);
            out[e] = p * inv;
        }
    } else {
        int g = (blockIdx.x - 1875) * 256 + t;       // 128*512
        int d = g >> 9, b = g & 511;
        float c0a = 0.f, c0b = 0.f, c0c = 0.f, c0d = 0.f;
        for (int s = 0; s < 80; s += 4) {
            c0a += part[(size_t)s * 65536 + g];
            c0b += part[(size_t)(s + 1) * 65536 + g];
            c0c += part[(size_t)(s + 2) * 65536 + g];
            c0d += part[(size_t)(s + 3) * 65536 + g];
        }
        float c0 = (c0a + c0b) + (c0c + c0d);
        float denom = 0.f;
        for (int k = 0; k < 64; ++k) denom = fmaf(phi1[d * 64 + k], theta1[k * NB + b], denom);
        denom = fmaxf(denom, EPSF);
        float xc = theta0[g] * c0;
        ratio1[g] = digammaf(denom + xc) - digammaf(denom);
    }
}

// ---------------------------------------------------------------- k78: R1 + NDot1 partials (blocks 0..255) | x2v (blocks 256..383)
__global__ __launch_bounds__(256) void k78(
    const float* __restrict__ ratio1, const float* __restrict__ theta1,
    const float* __restrict__ phi1, float* __restrict__ R1,
    float* __restrict__ ndp1, float* __restrict__ x2v)
{
    if (blockIdx.x < 256) {
        const int wid = (blockIdx.x << 2) + (threadIdx.x >> 6);  // 0..1023
        const int lane = threadIdx.x & 63;
        const int kk = wid & 63, dg = wid >> 6;                  // dg 0..15
        float th[8];
#pragma unroll
        for (int j = 0; j < 8; ++j) th[j] = theta1[kk * NB + j * 64 + lane];
        float ndp = 0.f;
#pragma unroll
        for (int dd = 0; dd < 8; ++dd) {
            int d = dg * 8 + dd;
            float s = 0.f;
#pragma unroll
            for (int j = 0; j < 8; ++j)
                s = fmaf(ratio1[d * NB + j * 64 + lane], th[j], s);
#pragma unroll
            for (int o = 1; o < 64; o <<= 1) s += __shfl_xor(s, o);
            if (lane == dd) {
                R1[d * 64 + kk] = s;
                ndp = phi1[d * 64 + kk] * s;
            }
        }
#pragma unroll
        for (int o = 1; o < 8; o <<= 1) ndp += __shfl_xor(ndp, o);
        if (lane == 0) ndp1[dg * 64 + kk] = 100.f * ndp;
    } else {
        int g = (blockIdx.x - 256) * 256 + threadIdx.x;  // 64*512
        int kk = g >> 9, b = g & 511;
        float s0 = 0.f, s1 = 0.f, s2 = 0.f, s3 = 0.f;
#pragma unroll 4
        for (int d = 0; d < 128; d += 4) {
            s0 = fmaf(phi1[d * 64 + kk],       ratio1[d * NB + b],       s0);
            s1 = fmaf(phi1[(d + 1) * 64 + kk], ratio1[(d + 1) * NB + b], s1);
            s2 = fmaf(phi1[(d + 2) * 64 + kk], ratio1[(d + 2) * NB + b], s2);
            s3 = fmaf(phi1[(d + 3) * 64 + kk], ratio1[(d + 3) * NB + b], s3);
        }
        x2v[g] = theta1[g] * ((s0 + s1) + (s2 + s3));
    }
}

// k10 (blocks 0..127) + tlasgr layer1 (blocks 128..159)
__global__ __launch_bounds__(256) void k10t1(
    const float* __restrict__ phi2, const float* __restrict__ theta2,
    const float* __restrict__ x2v, float* __restrict__ ratio2,
    const float* __restrict__ phi1, const float* __restrict__ R1,
    const float* __restrict__ noise1, const float* __restrict__ ndp1,
    float* __restrict__ out1)
{
    __shared__ float red[8];
    if (blockIdx.x < 128) {
        int g = blockIdx.x * 256 + threadIdx.x;       // 64*512
        int d = g >> 9, b = g & 511;
        float denom = 0.f;
        for (int k = 0; k < 32; ++k) denom = fmaf(phi2[d * 32 + k], theta2[k * NB + b], denom);
        denom = fmaxf(denom, EPSF);
        float xc = x2v[g];
        ratio2[g] = digammaf(denom + xc) - digammaf(denom);
    } else {
        const int t = threadIdx.x;
        const int c = t >> 7;                          // 0/1
        const int k = (blockIdx.x - 128) * 2 + c;
        const int d = t & 127;
        const int e = d * 64 + k;
        float ndv = 0.f;
#pragma unroll
        for (int i = 0; i < 16; ++i) ndv += ndp1[i * 64 + k];
        float inv_n = 1.f / fmaxf(ndv, EPSF);
        float tmpsum = ndv + 12.8f;
        float phiv = phi1[e];
        float tmp = fmaf(100.f * phiv, R1[e], 0.1f);
        float step = phiv + inv_n * (tmp - tmpsum * phiv) + sqrtf(2.f * inv_n * phiv) * noise1[e];
        float s = step;
#pragma unroll
        for (int o = 1; o < 64; o <<= 1) s += __shfl_xor(s, o);
        int slot = t >> 6;
        if ((t & 63) == 0) red[slot] = s;
        __syncthreads();
        float ssum = red[c * 2] + red[c * 2 + 1];
        float p = fmaxf(EPSF, step - (ssum - 1.f) * phiv);
        float q = p;
#pragma unroll
        for (int o = 1; o < 64; o <<= 1) q += __shfl_xor(q, o);
        if ((t & 63) == 0) red[4 + slot] = q;
        __syncthreads();
        float psum = red[4 + c * 2] + red[4 + c * 2 + 1];
        out1[e] = p / fmaxf(psum, EPSF);
    }
}

// ---------------------------------------------------------------- k11: R2 + NDot2 partials (no atomics)
__global__ __launch_bounds__(256) void k11_r2_w(
    const float* __restrict__ ratio2, const float* __restrict__ theta2,
    const float* __restrict__ phi2, float* __restrict__ R2, float* __restrict__ ndp2)
{
    const int wid = (blockIdx.x << 2) + (threadIdx.x >> 6);  // 0..255
    const int lane = threadIdx.x & 63;
    const int kk = wid & 31, dg = wid >> 5;                  // dg 0..7
    float th[8];
#pragma unroll
    for (int j = 0; j < 8; ++j) th[j] = theta2[kk * NB + j * 64 + lane];
    float ndp = 0.f;
#pragma unroll
    for (int dd = 0; dd < 8; ++dd) {
        int d = dg * 8 + dd;
        float s = 0.f;
#pragma unroll
        for (int j = 0; j < 8; ++j)
            s = fmaf(ratio2[d * NB + j * 64 + lane], th[j], s);
#pragma unroll
        for (int o = 1; o < 64; o <<= 1) s += __shfl_xor(s, o);
        if (lane == dd) {
            R2[d * 32 + kk] = s;
            ndp = phi2[d * 32 + kk] * s;
        }
    }
#pragma unroll
    for (int o = 1; o < 8; o <<= 1) ndp += __shfl_xor(ndp, o);
    if (lane == 0) ndp2[dg * 32 + kk] = 100.f * ndp;
}

// layer2 tlasgr: 4 columns per block (one wave each), D=64
__global__ __launch_bounds__(256) void t2_quad(
    const float* __restrict__ phi2, const float* __restrict__ R2,
    const float* __restrict__ noise2, const float* __restrict__ ndp2,
    float* __restrict__ out2)
{
    const int c = blockIdx.x * 4 + (threadIdx.x >> 6);
    const int d = threadIdx.x & 63;
    const int e = d * 32 + c;
    float ndv = 0.f;
#pragma unroll
    for (int i = 0; i < 8; ++i) ndv += ndp2[i * 32 + c];
    float inv_n = 1.f / fmaxf(ndv, EPSF);
    float tmpsum = ndv + 6.4f;
    float phiv = phi2[e];
    float tmp = fmaf(100.f * phiv, R2[e], 0.1f);
    float step = phiv + inv_n * (tmp - tmpsum * phiv) + sqrtf(2.f * inv_n * phiv) * noise2[e];
    float s = step;
#pragma unroll
    for (int o = 1; o < 64; o <<= 1) s += __shfl_xor(s, o);
    float p = fmaxf(EPSF, step - (s - 1.f) * phiv);
    float q = p;
#pragma unroll
    for (int o = 1; o < 64; o <<= 1) q += __shfl_xor(q, o);
    out2[e] = p / fmaxf(q, EPSF);
}

// ----------------------------------------------------------------
extern "C" void kernel_launch(void* const* d_in, const int* in_sizes, int n_in,
                              void* d_out, int out_size, void* d_ws, size_t ws_size,
                              hipStream_t stream)
{
    const float* x      = (const float*)d_in[0];
    const float* theta0 = (const float*)d_in[1];
    const float* theta1 = (const float*)d_in[2];
    const float* theta2 = (const float*)d_in[3];
    const float* phi0   = (const float*)d_in[4];
    const float* phi1   = (const float*)d_in[5];
    const float* phi2   = (const float*)d_in[6];
    const float* noise0 = (const float*)d_in[7];
    const float* noise1 = (const float*)d_in[8];
    const float* noise2 = (const float*)d_in[9];
    float* out = (float*)d_out;
    float* ws  = (float*)d_ws;

    unsigned short* ratioT = (unsigned short*)ws;              // (512,30080) bf16 = 7,700,480 fl
    unsigned short* phiT   = (unsigned short*)(ws + 7700480);  // (128,30080) bf16 = 1,925,120 fl
    unsigned short* thT_bf = (unsigned short*)(ws + 9625600);  // (512,128) = 32,768 fl
    unsigned short* th_bf  = (unsigned short*)(ws + 9658368);  // (128,512) = 32,768 fl
    float* part     = ws + 9691136;       // 80*65536 = 5,242,880
    float* NDot0    = ws + 14934016;      // 128 (zeroed)
    float* Sphi     = ws + 14934144;      // 128 (zeroed)
    float* Snz      = ws + 14934272;      // 128 (zeroed)
    float* ndp1     = ws + 14934400;      // 1024 (fully written each call)
    float* ndp2     = ws + 14935424;      // 256  (fully written each call)
    float* ratio1   = ws + 14935680;      // 65,536
    float* R1       = ws + 15001216;      // 8,192
    float* x2v      = ws + 15009408;      // 32,768
    float* ratio2   = ws + 15042176;      // 32,768
    float* R2       = ws + 15074944;      // 2,048  -> end 15,076,992 floats (60.3 MB)

    (void)hipMemsetAsync(NDot0, 0, 384 * sizeof(float), stream);

    pk_theta<<<64, 256, 0, stream>>>(theta0, th_bf, thT_bf);

    // layer 0 (R0 in d_out[0..3,840,000), transformed in place by k3456)
    kA1<<<1880, 512, 0, stream>>>(phi0, thT_bf, noise0, ratioT, phiT, Sphi, Snz);
    kA2<<<2048, 256, 0, stream>>>(x, ratioT);
    kBC<<<1110, 512, 0, stream>>>(ratioT, th_bf, phiT, phi0, out, NDot0, part);
    k3456<<<2131, 256, 0, stream>>>(phi0, noise0, NDot0, Sphi, Snz, out,
                                    phi1, theta1, theta0, part, ratio1);

    // layer 1 tail
    k78<<<384, 256, 0, stream>>>(ratio1, theta1, phi1, R1, ndp1, x2v);
    k10t1<<<160, 256, 0, stream>>>(phi2, theta2, x2v, ratio2,
                                   phi1, R1, noise1, ndp1, out + 3840000);

    // layer 2
    k11_r2_w<<<64, 256, 0, stream>>>(ratio2, theta2, phi2, R2, ndp2);
    t2_quad<<<8, 256, 0, stream>>>(phi2, R2, noise2, ndp2, out + 3848192);
}

// Round 18
// 133.168 us; speedup vs baseline: 1.1469x; 1.0038x over previous
//
#include <hip/hip_runtime.h>
#include <math.h>

#define EPSF 2.2e-10f
#define NV 30000
#define NVP 30080
#define NB 512

typedef __attribute__((ext_vector_type(8))) short short8;
typedef __attribute__((ext_vector_type(4))) float f32x4;
typedef __attribute__((ext_vector_type(4))) unsigned short ushort4v;

__device__ __forceinline__ unsigned short f2bf(float f) {
    unsigned int u = __float_as_uint(f);
    u += 0x7fffu + ((u >> 16) & 1u);
    return (unsigned short)(u >> 16);
}
__device__ __forceinline__ float bf2f(unsigned short h) {
    return __uint_as_float((unsigned int)h << 16);
}

// tiled scratch layouts (chunk-native: vt = v>>6, vo = v&63):
//   ratioT/denomT: [470][512][64]  addr = (vt<<15) + (b<<6) + vo
//   phiT:          [470][128][64]  addr = (vt<<13) + (k<<6) + vo

// ---------------------------------------------------------------- digamma
__device__ __forceinline__ float digammaf(float xx) {
    float x = xx, r = 0.f;
    while (x < 6.f) { r -= 1.f / x; x += 1.f; }
    float f = 1.f / (x * x);
    float s = logf(x) - 0.5f / x
        - f * (0.0833333333f - f * (0.0083333333f - f * (0.0039682540f
        - f * (0.0041666667f - f * 0.0075757576f))));
    return r + s;
}

// ================================================================ pk_theta
__global__ __launch_bounds__(256) void pk_theta(
    const float* __restrict__ th, unsigned short* __restrict__ th_bf,
    unsigned short* __restrict__ thT_bf)
{
    int idx = blockIdx.x * 256 + threadIdx.x;   // 16384 threads
    int k = idx >> 7, b4 = (idx & 127) << 2;
    float4 v = *(const float4*)&th[k * NB + b4];
    ushort4v h = { f2bf(v.x), f2bf(v.y), f2bf(v.z), f2bf(v.w) };
    *(ushort4v*)&th_bf[k * NB + b4] = h;
#pragma unroll
    for (int i = 0; i < 4; ++i) thT_bf[(b4 + i) * 128 + k] = h[i];
}

// ================================================================ kA1: denom GEMM (+phiT, Sphi, Snz)
// XCD-chunked remap (1880 = 8*235). Tiled outputs -> all stores sequential.
#define K1_PHI(v,k)    ((((v) << 8) + ((k) << 1)) ^ (((v) & 7) << 4))   // 64 rows x 256B = 16KB

__global__ __launch_bounds__(512, 8) void kA1(
    const float* __restrict__ phi0,            // (NV,128)
    const unsigned short* __restrict__ thT_bf, // (512,128)
    const float* __restrict__ noise0,          // (NV,128)
    unsigned short* __restrict__ denomT,       // tiled [470][512][64]
    unsigned short* __restrict__ phiT,         // tiled [470][128][64]
    float* __restrict__ Sphi,                  // (128)
    float* __restrict__ Snz)                   // (128)
{
    __shared__ __align__(16) unsigned char lds[18432];   // 16KB phi + 2KB red
    const int t = threadIdx.x, lane = t & 63, w = t >> 6;
    const int lrow = lane & 15, hi = lane >> 4;
    const int lkb = hi << 3, lcq = hi << 2;
    // XCD-chunked remap (bijective: 1880 = 8*235)
    const int slot = ((blockIdx.x & 7) * 235) + (blockIdx.x >> 3);
    const int vt = slot >> 2;                  // 0..469
    const int vbase = vt << 6;
    const int bslice = slot & 3;
    const int bb = (bslice << 7) + (w << 4);   // wave's 16 b-rows
    const size_t dbase = (size_t)vt << 15;     // denom tile base

    // stage phi (64 v-rows) -> bf16 LDS (zero pad beyond NV)
    for (int idx = t; idx < 1024; idx += 512) {
        int v = idx >> 4, kc = (idx & 15) << 3;
        int vg = vbase + v;
        float4 a = {0,0,0,0}, b = {0,0,0,0};
        if (vg < NV) {
            a = *(const float4*)&phi0[(size_t)vg * 128 + kc];
            b = *(const float4*)&phi0[(size_t)vg * 128 + kc + 4];
        }
        ushort4v h0 = { f2bf(a.x), f2bf(a.y), f2bf(a.z), f2bf(a.w) };
        ushort4v h1 = { f2bf(b.x), f2bf(b.y), f2bf(b.z), f2bf(b.w) };
        *(ushort4v*)&lds[K1_PHI(v, kc)]     = h0;
        *(ushort4v*)&lds[K1_PHI(v, kc + 4)] = h1;
    }
    __syncthreads();

    // phiT writeout (tiled -> 16KB sequential per block): only bslice 0
    if (bslice == 0) {
        const size_t pbase = (size_t)vt << 13;
        for (int idx = t; idx < 8192; idx += 512) {
            int v = idx & 63, k = idx >> 6;
            phiT[pbase + (k << 6) + v] = *(const unsigned short*)&lds[K1_PHI(v, k)];
        }
    }

    // denom MFMA: 4 v-frags x full K=128
    f32x4 dacc[4];
#pragma unroll
    for (int vg = 0; vg < 4; ++vg) dacc[vg] = (f32x4){0.f, 0.f, 0.f, 0.f};
#pragma unroll
    for (int ks = 0; ks < 4; ++ks) {
        short8 bt = *(const short8*)&thT_bf[(size_t)(bb + lrow) * 128 + (ks << 5) + lkb];
#pragma unroll
        for (int vg = 0; vg < 4; ++vg) {
            short8 pa = *(const short8*)&lds[K1_PHI(vg * 16 + lrow, (ks << 5) + lkb)];
            dacc[vg] = __builtin_amdgcn_mfma_f32_16x16x32_bf16(pa, bt, dacc[vg], 0, 0, 0);
        }
    }
    // store raw denom bf16 (tiled: block fills a contiguous 16KB region)
#pragma unroll
    for (int vg = 0; vg < 4; ++vg) {
        ushort4v h;
#pragma unroll
        for (int i = 0; i < 4; ++i) h[i] = f2bf(dacc[vg][i]);
        *(ushort4v*)&denomT[dbase + ((bb + lrow) << 6) + vg * 16 + lcq] = h;
    }

    // Sphi + Snz epilogue: only bslice 0 (phi LDS intact)
    if (bslice == 0) {
        const int kf = t & 127, vh = t >> 7;   // 4 v-groups of 16
        float sp = 0.f, sn = 0.f;
#pragma unroll
        for (int vi = 0; vi < 16; ++vi) {
            int v = (vh << 4) + vi;
            int vg = vbase + v;
            if (vg < NV) {
                float ph = bf2f(*(const unsigned short*)&lds[K1_PHI(v, kf)]);
                sp += ph;
                sn += sqrtf(ph) * noise0[(size_t)vg * 128 + kf];
            }
        }
        float* red = (float*)&lds[16384];
        red[t] = sp;
        __syncthreads();
        if (t < 128) atomicAdd(&Sphi[t], (red[t] + red[t + 128]) + (red[t + 256] + red[t + 384]));
        __syncthreads();
        red[t] = sn;
        __syncthreads();
        if (t < 128) atomicAdd(&Snz[t], (red[t] + red[t + 128]) + (red[t + 256] + red[t + 384]));
    }
}

// ================================================================ kA2: ratio = x * rcp(max(denom,eps)), IN PLACE (tiled)
__global__ __launch_bounds__(256, 8) void kA2(
    const float* __restrict__ x,          // (B,NV)
    unsigned short* __restrict__ ratioT)  // tiled [470][512][64]: denom in, ratio out
{
    const int b = blockIdx.x >> 2;
    const int q = blockIdx.x & 3;
    const float* xr = x + (size_t)b * NV;
    const int base = q * 7500;            // 1875 f32x4 per quarter
#pragma unroll
    for (int i = 0; i < 8; ++i) {
        int vi = i * 256 + threadIdx.x;
        if (vi < 1875) {
            int v = base + vi * 4;
            size_t ra = ((size_t)(v >> 6) << 15) + (b << 6) + (v & 63);
            f32x4 xv = *(const f32x4*)&xr[v];
            ushort4v dh = *(const ushort4v*)&ratioT[ra];
            ushort4v h;
#pragma unroll
            for (int j = 0; j < 4; ++j) {
                float den = fmaxf(bf2f(dh[j]), EPSF);
                h[j] = f2bf(xv[j] * __builtin_amdgcn_rcpf(den));
            }
            *(ushort4v*)&ratioT[ra] = h;
        }
    }
}

// ================================================================ kBC: kB (blocks 0..469) + k2 (blocks 470..1109)
#define KB_RT(v,b) ((((v) << 7) + ((b) << 1)) ^ (((((v) & 7) ^ (((v) >> 3) & 7))) << 4))
#define KB_R0(v,k) ((((v) << 9) + ((k) << 2)) ^ (((v) & 7) << 4))
#define K2_PH(k,v) ((((k) << 7) + ((v) << 1)) ^ (((k) & 7) << 4))
#define K2_RT(b,v) ((16384 + ((b) << 7) + ((v) << 1)) ^ (((b) & 7) << 4))

__global__ __launch_bounds__(512, 4) void kBC(
    const unsigned short* __restrict__ ratioT, // tiled [470][512][64]
    const unsigned short* __restrict__ th_bf,  // (128,512) bf16
    const unsigned short* __restrict__ phiT,   // tiled [470][128][64]
    const float* __restrict__ phi0,            // (NV,128)
    float* __restrict__ R0,                    // (NV,128) = d_out region
    float* __restrict__ NDot0,                 // (128)
    float* __restrict__ part)                  // (80,128,512)
{
    __shared__ __align__(16) unsigned char lds[32768];
    const int t = threadIdx.x, lane = t & 63, w = t >> 6;
    const int lrow = lane & 15, hi = lane >> 4;
    const int lkb = hi << 3, lcq = hi << 2;

    if (blockIdx.x < 470) {
        // ---------------- kB path ----------------
        const int vt = blockIdx.x;
        const int vbase = vt << 6;
        const size_t rbase = (size_t)vt << 15;
        f32x4 racc[4];
#pragma unroll
        for (int vf = 0; vf < 4; ++vf) racc[vf] = (f32x4){0.f, 0.f, 0.f, 0.f};

        for (int c = 0; c < 8; ++c) {
            const int bs = c << 6;
            __syncthreads();
            {
                int b = t >> 3, v8 = (t & 7) << 3;
                short8 val = *(const short8*)&ratioT[rbase + ((bs + b) << 6) + v8];
#pragma unroll
                for (int j = 0; j < 8; ++j)
                    *(unsigned short*)&lds[KB_RT(v8 + j, b)] = ((unsigned short*)&val)[j];
            }
            __syncthreads();
#pragma unroll
            for (int ks = 0; ks < 2; ++ks) {
                short8 a0 = *(const short8*)&th_bf[(size_t)(w * 16 + lrow) * NB + bs + (ks << 5) + lkb];
#pragma unroll
                for (int vf = 0; vf < 4; ++vf) {
                    short8 bb = *(const short8*)&lds[KB_RT(vf * 16 + lrow, (ks << 5) + lkb)];
                    racc[vf] = __builtin_amdgcn_mfma_f32_16x16x32_bf16(a0, bb, racc[vf], 0, 0, 0);
                }
            }
        }
        __syncthreads();
#pragma unroll
        for (int vf = 0; vf < 4; ++vf)
            *(f32x4*)&lds[KB_R0(vf * 16 + lrow, w * 16 + lcq)] = racc[vf];
        __syncthreads();
        const int kf = t & 127;
        float nd = 0.f;
        for (int idx = t; idx < 8192; idx += 512) {
            int v = idx >> 7;
            int vg = vbase + v;
            if (vg < NV) {
                float r0v = *(const float*)&lds[KB_R0(v, kf)];
                R0[(size_t)vg * 128 + kf] = r0v;
                nd += r0v * phi0[(size_t)vg * 128 + kf];
            }
        }
        __syncthreads();
        float* red = (float*)lds;
        red[t] = nd;
        __syncthreads();
        if (t < 128) atomicAdd(&NDot0[t], 100.f * ((red[t] + red[t + 128]) + (red[t + 256] + red[t + 384])));
    } else {
        // ---------------- k2 path ----------------
        const int bid2 = blockIdx.x - 470;
        // XCD-chunked remap (bijective: 640 = 8*80)
        const int slot = ((bid2 & 7) * 80) + (bid2 >> 3);
        const int btile = slot & 7;     // 8 b-tiles of 64
        const int split = slot >> 3;    // 80 splits
        const int b0 = btile << 6;

        f32x4 acc[4];
#pragma unroll
        for (int bt = 0; bt < 4; ++bt) acc[bt] = (f32x4){0.f, 0.f, 0.f, 0.f};

        for (int ci = split; ci < 470; ci += 80) {
            __syncthreads();
            for (int idx = t; idx < 1024; idx += 512) {      // phiT tile 128k x 64v (sequential slab)
                int k = idx >> 3, v8 = (idx & 7) << 3;
                *(short8*)&lds[K2_PH(k, v8)] =
                    *(const short8*)&phiT[((size_t)ci << 13) + (k << 6) + v8];
            }
            {                                                 // rat tile 64b x 64v (sequential)
                int b = t >> 3, v8 = (t & 7) << 3;
                *(short8*)&lds[K2_RT(b, v8)] =
                    *(const short8*)&ratioT[((size_t)ci << 15) + ((b0 + b) << 6) + v8];
            }
            __syncthreads();
#pragma unroll
            for (int vs = 0; vs < 2; ++vs) {
                short8 a0 = *(const short8*)&lds[K2_PH(w * 16 + lrow, (vs << 5) + lkb)];
#pragma unroll
                for (int bt = 0; bt < 4; ++bt) {
                    short8 bb = *(const short8*)&lds[K2_RT(bt * 16 + lrow, (vs << 5) + lkb)];
                    acc[bt] = __builtin_amdgcn_mfma_f32_16x16x32_bf16(a0, bb, acc[bt], 0, 0, 0);
                }
            }
        }
        float* dst = part + (size_t)split * 65536;
#pragma unroll
        for (int bt = 0; bt < 4; ++bt)
#pragma unroll
            for (int i = 0; i < 4; ++i)
                dst[(w * 16 + lcq + i) * NB + b0 + bt * 16 + lrow] = acc[bt][i];
    }
}

// ================================================================ k3456: k345 (blocks 0..1874) + k6 (blocks 1875..2130)
__global__ __launch_bounds__(256) void k3456(
    const float* __restrict__ phi0, const float* __restrict__ noise0,
    const float* __restrict__ NDot0, const float* __restrict__ Sphi,
    const float* __restrict__ Snz, float* __restrict__ out,
    const float* __restrict__ phi1, const float* __restrict__ theta1,
    const float* __restrict__ theta0, const float* __restrict__ part,
    float* __restrict__ ratio1)
{
    const int t = threadIdx.x;
    if (blockIdx.x < 1875) {
        const int k = t & 127;
        const size_t base = (size_t)blockIdx.x * 2048;
        float ndv = NDot0[k];
        float inv_n = 1.f / fmaxf(ndv, EPSF);
        float tmpsum = ndv + 3000.f;
        float sp = Sphi[k], sn = Snz[k];
        float stepsum = sp + inv_n * tmpsum * (1.f - sp) + sqrtf(2.f * inv_n) * sn;
        float ssm1 = stepsum - 1.f;
        float psum = stepsum - ssm1 * sp;
        float inv = 1.f / fmaxf(psum, EPSF);
#pragma unroll
        for (int i = 0; i < 8; ++i) {
            size_t e = base + i * 256 + t;
            float phi = phi0[e], R = out[e], nz = noise0[e];
            float tmp = fmaf(100.f * phi, R, 0.1f);
            float step = phi + inv_n * (tmp - tmpsum * phi) + sqrtf(2.f * inv_n * phi) * nz;
            float p = fmaxf(EPSF, step - ssm1 * phi);
            out[e] = p * inv;
        }
    } else {
        int g = (blockIdx.x - 1875) * 256 + t;       // 128*512
        int d = g >> 9, b = g & 511;
        float c0a = 0.f, c0b = 0.f, c0c = 0.f, c0d = 0.f;
        for (int s = 0; s < 80; s += 4) {
            c0a += part[(size_t)s * 65536 + g];
            c0b += part[(size_t)(s + 1) * 65536 + g];
            c0c += part[(size_t)(s + 2) * 65536 + g];
            c0d += part[(size_t)(s + 3) * 65536 + g];
        }
        float c0 = (c0a + c0b) + (c0c + c0d);
        float denom = 0.f;
        for (int k = 0; k < 64; ++k) denom = fmaf(phi1[d * 64 + k], theta1[k * NB + b], denom);
        denom = fmaxf(denom, EPSF);
        float xc = theta0[g] * c0;
        ratio1[g] = digammaf(denom + xc) - digammaf(denom);
    }
}

// ---------------------------------------------------------------- k78: R1 + NDot1 partials (blocks 0..255) | x2v (blocks 256..383)
__global__ __launch_bounds__(256) void k78(
    const float* __restrict__ ratio1, const float* __restrict__ theta1,
    const float* __restrict__ phi1, float* __restrict__ R1,
    float* __restrict__ ndp1, float* __restrict__ x2v)
{
    if (blockIdx.x < 256) {
        const int wid = (blockIdx.x << 2) + (threadIdx.x >> 6);  // 0..1023
        const int lane = threadIdx.x & 63;
        const int kk = wid & 63, dg = wid >> 6;                  // dg 0..15
        float th[8];
#pragma unroll
        for (int j = 0; j < 8; ++j) th[j] = theta1[kk * NB + j * 64 + lane];
        float ndp = 0.f;
#pragma unroll
        for (int dd = 0; dd < 8; ++dd) {
            int d = dg * 8 + dd;
            float s = 0.f;
#pragma unroll
            for (int j = 0; j < 8; ++j)
                s = fmaf(ratio1[d * NB + j * 64 + lane], th[j], s);
#pragma unroll
            for (int o = 1; o < 64; o <<= 1) s += __shfl_xor(s, o);
            if (lane == dd) {
                R1[d * 64 + kk] = s;
                ndp = phi1[d * 64 + kk] * s;
            }
        }
#pragma unroll
        for (int o = 1; o < 8; o <<= 1) ndp += __shfl_xor(ndp, o);
        if (lane == 0) ndp1[dg * 64 + kk] = 100.f * ndp;
    } else {
        int g = (blockIdx.x - 256) * 256 + threadIdx.x;  // 64*512
        int kk = g >> 9, b = g & 511;
        float s0 = 0.f, s1 = 0.f, s2 = 0.f, s3 = 0.f;
#pragma unroll 4
        for (int d = 0; d < 128; d += 4) {
            s0 = fmaf(phi1[d * 64 + kk],       ratio1[d * NB + b],       s0);
            s1 = fmaf(phi1[(d + 1) * 64 + kk], ratio1[(d + 1) * NB + b], s1);
            s2 = fmaf(phi1[(d + 2) * 64 + kk], ratio1[(d + 2) * NB + b], s2);
            s3 = fmaf(phi1[(d + 3) * 64 + kk], ratio1[(d + 3) * NB + b], s3);
        }
        x2v[g] = theta1[g] * ((s0 + s1) + (s2 + s3));
    }
}

// k10 (blocks 0..127) + tlasgr layer1 (blocks 128..159)
__global__ __launch_bounds__(256) void k10t1(
    const float* __restrict__ phi2, const float* __restrict__ theta2,
    const float* __restrict__ x2v, float* __restrict__ ratio2,
    const float* __restrict__ phi1, const float* __restrict__ R1,
    const float* __restrict__ noise1, const float* __restrict__ ndp1,
    float* __restrict__ out1)
{
    __shared__ float red[8];
    if (blockIdx.x < 128) {
        int g = blockIdx.x * 256 + threadIdx.x;       // 64*512
        int d = g >> 9, b = g & 511;
        float denom = 0.f;
        for (int k = 0; k < 32; ++k) denom = fmaf(phi2[d * 32 + k], theta2[k * NB + b], denom);
        denom = fmaxf(denom, EPSF);
        float xc = x2v[g];
        ratio2[g] = digammaf(denom + xc) - digammaf(denom);
    } else {
        const int t = threadIdx.x;
        const int c = t >> 7;                          // 0/1
        const int k = (blockIdx.x - 128) * 2 + c;
        const int d = t & 127;
        const int e = d * 64 + k;
        float ndv = 0.f;
#pragma unroll
        for (int i = 0; i < 16; ++i) ndv += ndp1[i * 64 + k];
        float inv_n = 1.f / fmaxf(ndv, EPSF);
        float tmpsum = ndv + 12.8f;
        float phiv = phi1[e];
        float tmp = fmaf(100.f * phiv, R1[e], 0.1f);
        float step = phiv + inv_n * (tmp - tmpsum * phiv) + sqrtf(2.f * inv_n * phiv) * noise1[e];
        float s = step;
#pragma unroll
        for (int o = 1; o < 64; o <<= 1) s += __shfl_xor(s, o);
        int slot = t >> 6;
        if ((t & 63) == 0) red[slot] = s;
        __syncthreads();
        float ssum = red[c * 2] + red[c * 2 + 1];
        float p = fmaxf(EPSF, step - (ssum - 1.f) * phiv);
        float q = p;
#pragma unroll
        for (int o = 1; o < 64; o <<= 1) q += __shfl_xor(q, o);
        if ((t & 63) == 0) red[4 + slot] = q;
        __syncthreads();
        float psum = red[4 + c * 2] + red[4 + c * 2 + 1];
        out1[e] = p / fmaxf(psum, EPSF);
    }
}

// ---------------------------------------------------------------- k11: R2 + NDot2 partials (no atomics)
__global__ __launch_bounds__(256) void k11_r2_w(
    const float* __restrict__ ratio2, const float* __restrict__ theta2,
    const float* __restrict__ phi2, float* __restrict__ R2, float* __restrict__ ndp2)
{
    const int wid = (blockIdx.x << 2) + (threadIdx.x >> 6);  // 0..255
    const int lane = threadIdx.x & 63;
    const int kk = wid & 31, dg = wid >> 5;                  // dg 0..7
    float th[8];
#pragma unroll
    for (int j = 0; j < 8; ++j) th[j] = theta2[kk * NB + j * 64 + lane];
    float ndp = 0.f;
#pragma unroll
    for (int dd = 0; dd < 8; ++dd) {
        int d = dg * 8 + dd;
        float s = 0.f;
#pragma unroll
        for (int j = 0; j < 8; ++j)
            s = fmaf(ratio2[d * NB + j * 64 + lane], th[j], s);
#pragma unroll
        for (int o = 1; o < 64; o <<= 1) s += __shfl_xor(s, o);
        if (lane == dd) {
            R2[d * 32 + kk] = s;
            ndp = phi2[d * 32 + kk] * s;
        }
    }
#pragma unroll
    for (int o = 1; o < 8; o <<= 1) ndp += __shfl_xor(ndp, o);
    if (lane == 0) ndp2[dg * 32 + kk] = 100.f * ndp;
}

// layer2 tlasgr: 4 columns per block (one wave each), D=64
__global__ __launch_bounds__(256) void t2_quad(
    const float* __restrict__ phi2, const float* __restrict__ R2,
    const float* __restrict__ noise2, const float* __restrict__ ndp2,
    float* __restrict__ out2)
{
    const int c = blockIdx.x * 4 + (threadIdx.x >> 6);
    const int d = threadIdx.x & 63;
    const int e = d * 32 + c;
    float ndv = 0.f;
#pragma unroll
    for (int i = 0; i < 8; ++i) ndv += ndp2[i * 32 + c];
    float inv_n = 1.f / fmaxf(ndv, EPSF);
    float tmpsum = ndv + 6.4f;
    float phiv = phi2[e];
    float tmp = fmaf(100.f * phiv, R2[e], 0.1f);
    float step = phiv + inv_n * (tmp - tmpsum * phiv) + sqrtf(2.f * inv_n * phiv) * noise2[e];
    float s = step;
#pragma unroll
    for (int o = 1; o < 64; o <<= 1) s += __shfl_xor(s, o);
    float p = fmaxf(EPSF, step - (s - 1.f) * phiv);
    float q = p;
#pragma unroll
    for (int o = 1; o < 64; o <<= 1) q += __shfl_xor(q, o);
    out2[e] = p / fmaxf(q, EPSF);
}

// ----------------------------------------------------------------
extern "C" void kernel_launch(void* const* d_in, const int* in_sizes, int n_in,
                              void* d_out, int out_size, void* d_ws, size_t ws_size,
                              hipStream_t stream)
{
    const float* x      = (const float*)d_in[0];
    const float* theta0 = (const float*)d_in[1];
    const float* theta1 = (const float*)d_in[2];
    const float* theta2 = (const float*)d_in[3];
    const float* phi0   = (const float*)d_in[4];
    const float* phi1   = (const float*)d_in[5];
    const float* phi2   = (const float*)d_in[6];
    const float* noise0 = (const float*)d_in[7];
    const float* noise1 = (const float*)d_in[8];
    const float* noise2 = (const float*)d_in[9];
    float* out = (float*)d_out;
    float* ws  = (float*)d_ws;

    unsigned short* ratioT = (unsigned short*)ws;              // tiled [470][512][64] = 7,700,480 fl
    unsigned short* phiT   = (unsigned short*)(ws + 7700480);  // tiled [470][128][64] = 1,925,120 fl
    unsigned short* thT_bf = (unsigned short*)(ws + 9625600);  // (512,128) = 32,768 fl
    unsigned short* th_bf  = (unsigned short*)(ws + 9658368);  // (128,512) = 32,768 fl
    float* part     = ws + 9691136;       // 80*65536 = 5,242,880
    float* NDot0    = ws + 14934016;      // 128 (zeroed)
    float* Sphi     = ws + 14934144;      // 128 (zeroed)
    float* Snz      = ws + 14934272;      // 128 (zeroed)
    float* ndp1     = ws + 14934400;      // 1024 (fully written each call)
    float* ndp2     = ws + 14935424;      // 256  (fully written each call)
    float* ratio1   = ws + 14935680;      // 65,536
    float* R1       = ws + 15001216;      // 8,192
    float* x2v      = ws + 15009408;      // 32,768
    float* ratio2   = ws + 15042176;      // 32,768
    float* R2       = ws + 15074944;      // 2,048  -> end 15,076,992 floats (60.3 MB)

    (void)hipMemsetAsync(NDot0, 0, 384 * sizeof(float), stream);

    pk_theta<<<64, 256, 0, stream>>>(theta0, th_bf, thT_bf);

    // layer 0 (R0 in d_out[0..3,840,000), transformed in place by k3456)
    kA1<<<1880, 512, 0, stream>>>(phi0, thT_bf, noise0, ratioT, phiT, Sphi, Snz);
    kA2<<<2048, 256, 0, stream>>>(x, ratioT);
    kBC<<<1110, 512, 0, stream>>>(ratioT, th_bf, phiT, phi0, out, NDot0, part);
    k3456<<<2131, 256, 0, stream>>>(phi0, noise0, NDot0, Sphi, Snz, out,
                                    phi1, theta1, theta0, part, ratio1);

    // layer 1 tail
    k78<<<384, 256, 0, stream>>>(ratio1, theta1, phi1, R1, ndp1, x2v);
    k10t1<<<160, 256, 0, stream>>>(phi2, theta2, x2v, ratio2,
                                   phi1, R1, noise1, ndp1, out + 3840000);

    // layer 2
    k11_r2_w<<<64, 256, 0, stream>>>(ratio2, theta2, phi2, R2, ndp2);
    t2_quad<<<8, 256, 0, stream>>>(phi2, R2, noise2, ndp2, out + 3848192);
}